// Round 14
// baseline (157.902 us; speedup 1.0000x reference)
//
#include <hip/hip_runtime.h>
#include <math.h>

typedef unsigned short ushort_t;
typedef unsigned int uint_t;
typedef _Float16 half_t;

#define DIMC 128
#define NB 16
#define NL 4096

using f32x4 = __attribute__((ext_vector_type(4))) float;
using bf16x8 = __attribute__((ext_vector_type(8))) short;
using half4 = __attribute__((ext_vector_type(4))) half_t;

__device__ __forceinline__ ushort_t bf16rne(float f) {
  uint_t b = __float_as_uint(f);
  b += 0x7fffu + ((b >> 16) & 1u);
  return (ushort_t)(b >> 16);
}

__device__ __forceinline__ uint_t pkbf(float lo, float hi) {
  union { __bf16 h[2]; uint_t u; } u;
  u.h[0] = (__bf16)lo;   // fptrunc = RNE
  u.h[1] = (__bf16)hi;
  return u.u;
}

__device__ __forceinline__ float bf2f(ushort_t u) {
  return __uint_as_float(((uint_t)u) << 16);
}

// LDS-only barrier: publish ds_writes (lgkmcnt) and sync waves WITHOUT
// draining vmcnt -- global B prefetches stay in flight across it (T3/T4).
__device__ __forceinline__ void lds_barrier() {
  asm volatile("s_waitcnt lgkmcnt(0)" ::: "memory");
  __builtin_amdgcn_s_barrier();
  asm volatile("" ::: "memory");
}

// ---------------- kernel 0: coeffs -> B-fragment order, bf16 ----------------
// flat 16B-fragment id (per layer): G = ((ci*8 + n)*4 + s)*64 + l
// element j: col o = n*16 + (l&15); k = ci*128 + s*32 + (l>>4)*8 + j
// k -> trig=k&1, g=(k>>1)&7, i=k>>4 ; value = fk[trig][o][i][g]
__global__ __launch_bounds__(256) void prep_coef_k(const float* __restrict__ fk1,
                                                   const float* __restrict__ fk2,
                                                   ushort_t* __restrict__ coefT) {
  int idx = blockIdx.x * 256 + threadIdx.x;  // fragment id, 65536 total
  int layer = idx >> 15;
  int rem = idx & 32767;
  int ci = rem >> 11;
  int n = (rem >> 8) & 7;
  int s = (rem >> 6) & 3;
  int l = rem & 63;
  int o = n * 16 + (l & 15);
  int kbase = ci * 128 + s * 32 + (l >> 4) * 8;
  const float* src = layer ? fk2 : fk1;
  uint_t p[4];
#pragma unroll
  for (int jj = 0; jj < 4; ++jj) {
    int k0 = kbase + jj * 2;
    int t0 = k0 & 1, g0 = (k0 >> 1) & 7, i0 = k0 >> 4;
    int k1 = k0 + 1;
    int t1 = k1 & 1, g1 = (k1 >> 1) & 7, i1 = k1 >> 4;
    ushort_t a = bf16rne(src[((t0 * DIMC + o) * DIMC + i0) * 8 + g0]);
    ushort_t b = bf16rne(src[((t1 * DIMC + o) * DIMC + i1) * 8 + g1]);
    p[jj] = (uint_t)a | ((uint_t)b << 16);
  }
  uint4 w;
  w.x = p[0]; w.y = p[1]; w.z = p[2]; w.w = p[3];
  *(uint4*)&coefT[idx * 8] = w;
}

// ---------------- kernel 1: LN1 -> FKAN1(MFMA) -> ReLU -> LN2 -> FKAN2(MFMA) ----
// Block = 128 tokens x 128 outputs, 4 waves in a 2x2 tile: wave (mw,nw) owns
// 64 tokens x 64 outputs. A-fragments produced ONCE per block per s-step
// (256 threads = 1 chain each) into a double-buffered feat store; B fragments
// (4/wave-step) from L2, prefetched one step ahead ACROSS lds_barrier.
constexpr int SXH = 132;  // xln row stride in halfwords (rows 8B-aligned)

__global__ __launch_bounds__(256, 2) void fkan_main_k(
    const float* __restrict__ x,
    const float* __restrict__ n1g, const float* __restrict__ n1b,
    const float* __restrict__ fk1b,
    const float* __restrict__ n2g, const float* __restrict__ n2b,
    const float* __restrict__ fk2b,
    const ushort_t* __restrict__ coefT,
    ushort_t* __restrict__ out2,
    float* __restrict__ chanSum, float* __restrict__ chanMax) {

  __shared__ half_t xln[128 * SXH];   // 33.8 KB
  __shared__ uint4 feat[2][8][64];    // 16 KB: [buf][m-tile][fraglane]
  __shared__ float sredS[4][2], sredM[4][2];

  const int tid = threadIdx.x;
  const int bid = blockIdx.x;                        // 512 blocks = 128 tokens
  const int lane = tid & 63;
  const int wid = tid >> 6;
  const int mw = wid >> 1;                           // token half (64 rows)
  const int nw = wid & 1;                            // output half (64 cols)
  const size_t tileBase = (size_t)bid * 128 * DIMC;

  {  // block x-load: 128 rows x 128 f32, coalesced; fp16 to LDS
    const float4* src = (const float4*)(x + tileBase);
#pragma unroll
    for (int j = 0; j < 16; ++j) {
      int idx = j * 256 + tid;  // 0..4095
      float4 v = src[idx];
      half4 h;
      h.x = (half_t)v.x; h.y = (half_t)v.y; h.z = (half_t)v.z; h.w = (half_t)v.w;
      *(half4*)&xln[(idx >> 5) * SXH + (idx & 31) * 4] = h;
    }
  }
  __syncthreads();

  auto layernorm = [&](const float* gg, const float* bb) {  // 32 rows/wave
    float g0 = gg[lane], g1 = gg[lane + 64];
    float be0 = bb[lane], be1 = bb[lane + 64];
#pragma unroll
    for (int j = 0; j < 32; ++j) {
      int t = wid * 32 + j;
      float v0 = (float)xln[t * SXH + lane], v1 = (float)xln[t * SXH + 64 + lane];
      float s = v0 + v1, q = v0 * v0 + v1 * v1;
#pragma unroll
      for (int m = 1; m < 64; m <<= 1) {
        s += __shfl_xor(s, m, 64);
        q += __shfl_xor(q, m, 64);
      }
      float mean = s * (1.0f / DIMC);
      float var = q * (1.0f / DIMC) - mean * mean;
      float rr = rsqrtf(var + 1e-5f);
      xln[t * SXH + lane] = (half_t)((v0 - mean) * rr * g0 + be0);
      xln[t * SXH + 64 + lane] = (half_t)((v1 - mean) * rr * g1 + be1);
    }
  };

  layernorm(n1g, n1b);
  __syncthreads();

  // featgen: thread -> token ft = tid&127, channel-offset fco = tid>>7.
  // One 8-harmonic chain per thread per s-step = the block's full A set.
  // Frag layout: m-tile ft>>4, lane (ft&15) + 16*(2*fco + hb).
  const int ft = tid & 127;
  const int fco = tid >> 7;
  const int fmt = ft >> 4;
  const int fslot = (ft & 15) + (fco << 5);
  const half_t* fx = &xln[ft * SXH];

  auto chain_gen = [&](int step, int nbuf) {
    float a = (float)fx[((step >> 2) & 15) * 8 + (step & 3) * 2 + fco];
    float s1, c1;
    __sincosf(a, &s1, &c1);
    uint_t q0 = pkbf(c1, s1);
    float ck = c1, sk = s1, cn, sn;
    cn = ck * c1 - sk * s1; sn = sk * c1 + ck * s1; ck = cn; sk = sn;
    uint_t q1 = pkbf(ck, sk);
    cn = ck * c1 - sk * s1; sn = sk * c1 + ck * s1; ck = cn; sk = sn;
    uint_t q2 = pkbf(ck, sk);
    cn = ck * c1 - sk * s1; sn = sk * c1 + ck * s1; ck = cn; sk = sn;
    uint_t q3 = pkbf(ck, sk);
    cn = ck * c1 - sk * s1; sn = sk * c1 + ck * s1; ck = cn; sk = sn;
    uint_t q4 = pkbf(ck, sk);
    cn = ck * c1 - sk * s1; sn = sk * c1 + ck * s1; ck = cn; sk = sn;
    uint_t q5 = pkbf(ck, sk);
    cn = ck * c1 - sk * s1; sn = sk * c1 + ck * s1; ck = cn; sk = sn;
    uint_t q6 = pkbf(ck, sk);
    cn = ck * c1 - sk * s1; sn = sk * c1 + ck * s1; ck = cn; sk = sn;
    uint_t q7 = pkbf(ck, sk);
    uint4 w0; w0.x = q0; w0.y = q1; w0.z = q2; w0.w = q3;  // harmonics 1-4
    uint4 w1; w1.x = q4; w1.y = q5; w1.z = q6; w1.w = q7;  // harmonics 5-8
    feat[nbuf][fmt][fslot] = w0;
    feat[nbuf][fmt][fslot + 16] = w1;
  };

  f32x4 acc[4][4];  // [nt][mt]

  auto ldB = [&](const ushort_t* cbase, int step, bf16x8 (&bf)[4]) {
    int ci = (step >> 2) & 15, s = step & 3;
#pragma unroll
    for (int nt = 0; nt < 4; ++nt)
      bf[nt] = *(const bf16x8*)(cbase +
          (size_t)((((ci * 8 + nw * 4 + nt) * 4 + s) << 6) + lane) * 8);
  };

  auto do_step = [&](const ushort_t* cbase, int step, int par,
                     bf16x8 (&bfCur)[4], bf16x8 (&bfNext)[4]) {
    bf16x8 af[4];
#pragma unroll
    for (int k = 0; k < 4; ++k)
      af[k] = *(const bf16x8*)&feat[par][mw * 4 + k][lane];
    ldB(cbase, step + 1, bfNext);     // prefetch: stays in flight across barrier
    chain_gen(step + 1, par ^ 1);     // produce next step's A set
    __builtin_amdgcn_s_setprio(1);
#pragma unroll
    for (int nt = 0; nt < 4; ++nt)
#pragma unroll
      for (int mt = 0; mt < 4; ++mt)
        acc[nt][mt] = __builtin_amdgcn_mfma_f32_16x16x32_bf16(
            af[mt], bfCur[nt], acc[nt][mt], 0, 0, 0);
    __builtin_amdgcn_s_setprio(0);
    lds_barrier();
  };

  auto run_layer = [&](const ushort_t* cbase) {
#pragma unroll
    for (int nt = 0; nt < 4; ++nt)
#pragma unroll
      for (int mt = 0; mt < 4; ++mt) acc[nt][mt] = (f32x4)(0.f);
    bf16x8 bfA[4], bfB[4];
    ldB(cbase, 0, bfA);
    chain_gen(0, 0);
    lds_barrier();
#pragma unroll 1
    for (int it = 0; it < 32; ++it) {
      do_step(cbase, it * 2, 0, bfA, bfB);
      do_step(cbase, it * 2 + 1, 1, bfB, bfA);
    }
  };

  run_layer(coefT);
  __syncthreads();

  // FKAN1 epilogue: bias + ReLU -> xln (C/D: col=lane&15, row=(lane>>4)*4+r)
#pragma unroll
  for (int nt = 0; nt < 4; ++nt) {
    int o = nw * 64 + nt * 16 + (lane & 15);
    float bia = fk1b[o];
#pragma unroll
    for (int mt = 0; mt < 4; ++mt) {
      int trow = mw * 64 + mt * 16 + (lane >> 4) * 4;
#pragma unroll
      for (int r = 0; r < 4; ++r)
        xln[(trow + r) * SXH + o] = (half_t)fmaxf(acc[nt][mt][r] + bia, 0.f);
    }
  }
  __syncthreads();

  layernorm(n2g, n2b);
  __syncthreads();

  run_layer(coefT + 262144);
  __syncthreads();

  // FKAN2 epilogue: bias -> out2 (bf16) + channel-group partial stats
  float ls0 = 0.f, ls1 = 0.f, lm0 = -INFINITY, lm1 = -INFINITY;
#pragma unroll
  for (int nt = 0; nt < 4; ++nt) {
    int o = nw * 64 + nt * 16 + (lane & 15);
    float bia = fk2b[o];
#pragma unroll
    for (int mt = 0; mt < 4; ++mt) {
      int trow = mw * 64 + mt * 16 + (lane >> 4) * 4;
#pragma unroll
      for (int r = 0; r < 4; ++r) {
        float v = acc[nt][mt][r] + bia;
        out2[tileBase + (size_t)(trow + r) * DIMC + o] = bf16rne(v);
        if (mt < 2) { ls0 += v; lm0 = fmaxf(lm0, v); }
        else        { ls1 += v; lm1 = fmaxf(lm1, v); }
      }
    }
  }
#pragma unroll
  for (int m = 1; m < 64; m <<= 1) {
    ls0 += __shfl_xor(ls0, m, 64);
    ls1 += __shfl_xor(ls1, m, 64);
    lm0 = fmaxf(lm0, __shfl_xor(lm0, m, 64));
    lm1 = fmaxf(lm1, __shfl_xor(lm1, m, 64));
  }
  if (lane == 0) {  // groups 2mw (tokens mw*64..+31), 2mw+1 (+32..+63)
    sredS[2 * mw + 0][nw] = ls0;
    sredS[2 * mw + 1][nw] = ls1;
    sredM[2 * mw + 0][nw] = lm0;
    sredM[2 * mw + 1][nw] = lm1;
  }
  __syncthreads();
  if (tid < 4) {
    chanSum[bid * 4 + tid] = sredS[tid][0] + sredS[tid][1];
    chanMax[bid * 4 + tid] = fmaxf(sredM[tid][0], sredM[tid][1]);
  }
}

// ---------------- kernel 2: fused tail: chan-MLP + spatial stats + conv + apply ----
__global__ __launch_bounds__(128) void tail_k(
    const float* __restrict__ x, const ushort_t* __restrict__ out2,
    const float* __restrict__ chanSum, const float* __restrict__ chanMax,
    const float* __restrict__ w1, const float* __restrict__ w2,
    const float* __restrict__ convw, float* __restrict__ dout) {
  int b = blockIdx.x >> 5;
  int t = blockIdx.x & 31;
  int c = threadIdx.x;
  __shared__ float avs[DIMC], mxs[DIMC], hh[16], cas[DIMC];
  __shared__ float sM[134], sX[134];

  avs[c] = chanSum[b * DIMC + c] * (1.0f / NL);
  mxs[c] = chanMax[b * DIMC + c];
  __syncthreads();
  if (c < 16) {
    const float* v = (c < 8) ? avs : mxs;
    float a = 0.f;
    for (int i = 0; i < DIMC; ++i) a += v[i] * w1[(c & 7) * DIMC + i];
    hh[c] = fmaxf(a, 0.f);
  }
  __syncthreads();
  {
    float z = 0.f;
#pragma unroll
    for (int r = 0; r < 8; ++r) z += (hh[r] + hh[8 + r]) * w2[c * 8 + r];
    cas[c] = 1.0f / (1.0f + expf(-z));
  }
  __syncthreads();

  const ushort_t* o2b = out2 + (size_t)b * NL * DIMC;
  float s = 0.f, m = -INFINITY;
#pragma unroll 4
  for (int c4 = 0; c4 < 128; ++c4) {
    float v = bf2f(o2b[(size_t)(c4 * 32 + t) * DIMC + c]) * cas[c4];
    s += v;
    m = fmaxf(m, v);
  }
  sM[c + 3] = s * (1.0f / DIMC);
  sX[c + 3] = m;
  if (c < 6) {  // halo positions (zero-padded at sequence edges)
    bool left = c < 3;
    int tp = left ? t - 1 : t + 1;
    int cc = left ? 125 + c : c - 3;
    int di = left ? c : 131 + (c - 3);
    float ss = 0.f, mm2 = -INFINITY;
    if (tp >= 0 && tp < 32) {
#pragma unroll 4
      for (int c4 = 0; c4 < 128; ++c4) {
        float v = bf2f(o2b[(size_t)(c4 * 32 + tp) * DIMC + cc]) * cas[c4];
        ss += v;
        mm2 = fmaxf(mm2, v);
      }
      sM[di] = ss * (1.0f / DIMC);
      sX[di] = mm2;
    } else {
      sM[di] = 0.f;
      sX[di] = 0.f;
    }
  }
  __syncthreads();

  float sa = 0.f;
#pragma unroll
  for (int d = 0; d < 7; ++d)
    sa += convw[21 + d] * sM[c + d] + convw[70 + d] * sX[c + d];
  float sig = 1.0f / (1.0f + expf(-sa));

  const float* xb = x + (size_t)b * NL * DIMC;
  float* db = dout + (size_t)b * NL * DIMC;
#pragma unroll 2
  for (int c4 = 0; c4 < 128; ++c4) {
    size_t idx = (size_t)(c4 * 32 + t) * DIMC + c;
    db[idx] = xb[idx] + bf2f(o2b[idx]) * cas[c4] * sig;
  }
}

// ---------------- launch ----------------
extern "C" void kernel_launch(void* const* d_in, const int* in_sizes, int n_in,
                              void* d_out, int out_size, void* d_ws, size_t ws_size,
                              hipStream_t stream) {
  const float* x = (const float*)d_in[0];
  const float* n1g = (const float*)d_in[1];
  const float* n1b = (const float*)d_in[2];
  const float* fk1c = (const float*)d_in[3];
  const float* fk1b = (const float*)d_in[4];
  const float* n2g = (const float*)d_in[5];
  const float* n2b = (const float*)d_in[6];
  const float* fk2c = (const float*)d_in[7];
  const float* fk2b = (const float*)d_in[8];
  const float* w1 = (const float*)d_in[9];
  const float* w2 = (const float*)d_in[10];
  const float* convw = (const float*)d_in[11];

  ushort_t* out2 = (ushort_t*)d_ws;        // 8,388,608 bf16 (16 MB)
  ushort_t* coefT = out2 + 8388608;        // 524,288 bf16 (1 MB)
  float* chanSum = (float*)(coefT + 524288);
  float* chanMax = chanSum + 2048;
  float* dout = (float*)d_out;

  prep_coef_k<<<256, 256, 0, stream>>>(fk1c, fk2c, coefT);
  fkan_main_k<<<512, 256, 0, stream>>>(x, n1g, n1b, fk1b, n2g, n2b,
                                       fk2b, coefT, out2, chanSum, chanMax);
  tail_k<<<NB * 32, 128, 0, stream>>>(x, out2, chanSum, chanMax, w1, w2, convw, dout);
}